// Round 1
// baseline (29.635 us; speedup 1.0000x reference)
//
#include <hip/hip_runtime.h>
#include <hip/hip_bf16.h>

#define NPTS 20000
#define KNB 13
#define CH 32            // INP == OUT == 32
#define PTS_PER_BLOCK 8  // 8 points * 32 channels = 256 threads

// Per-point precomputed contribution G[j][o]  (f32), plus mask-mode flag.
__device__ float g_G[NPTS * CH];
__device__ int g_mask_is_bytes;

// ---------------------------------------------------------------------------
// Detect whether nbr_mask buffer is 1-byte bool or 4-byte int32.
// int32 layout of 0/1 values => every byte at offset p%4!=0 is 0.
// bool layout (random 0/1 bytes) => ~3/4 of sampled bytes nonzero w.p. ~1.
// Samples first 4096 bytes (both layouts are >= 260000 bytes, safe).
// ---------------------------------------------------------------------------
__global__ void detect_mask_mode(const unsigned char* __restrict__ mb) {
    int l = threadIdx.x;  // 64 lanes
    int found = 0;
    #pragma unroll
    for (int s = 0; s < 64; ++s) {
        int p = l * 64 + s;
        if ((p & 3) != 0 && mb[p] != 0) found = 1;
    }
    unsigned long long anyb = __ballot(found);
    if (l == 0) g_mask_is_bytes = (anyb != 0ull) ? 1 : 0;
}

// ---------------------------------------------------------------------------
// Phase 1: G[j][o] = sum_d coords[j][d] * (feats[j] . W[d][:,o]) + feats[j].B[:,o]
// W,b staged in LDS as Wb[4][1024] (W0,W1,W2,b-as-matrix).
// Thread t: local point lj = t>>5, out channel o = t&31.
// ---------------------------------------------------------------------------
__global__ __launch_bounds__(256) void precompute_G(
    const float* __restrict__ feats, const float* __restrict__ coords,
    const float* __restrict__ W, const float* __restrict__ b) {
    __shared__ float Wb[4][CH * CH];          // 16 KB
    __shared__ float fsh[PTS_PER_BLOCK][CH];  // 1 KB
    __shared__ float csh[PTS_PER_BLOCK][3];

    const int t = threadIdx.x;
    const int base = blockIdx.x * PTS_PER_BLOCK;

    // Stage W (3072 f32 = 768 float4) + b (256 float4) into LDS.
    const float4* W4 = (const float4*)W;
    const float4* b4 = (const float4*)b;
    float4* Wb4 = (float4*)&Wb[0][0];
    #pragma unroll
    for (int r = 0; r < 3; ++r) Wb4[t + 256 * r] = W4[t + 256 * r];
    Wb4[768 + t] = b4[t];

    // Stage feats tile (coalesced: index = blockIdx*256 + t) and coords.
    fsh[t >> 5][t & 31] = feats[base * CH + t];
    if (t < PTS_PER_BLOCK * 3) csh[t / 3][t % 3] = coords[base * 3 + t];
    __syncthreads();

    const int lj = t >> 5;
    const int o  = t & 31;
    float a0 = 0.f, a1 = 0.f, a2 = 0.f, a3 = 0.f;
    #pragma unroll
    for (int i = 0; i < CH; ++i) {
        const float f = fsh[lj][i];
        a0 += f * Wb[0][i * CH + o];   // lanes o=0..31 -> consecutive banks
        a1 += f * Wb[1][i * CH + o];
        a2 += f * Wb[2][i * CH + o];
        a3 += f * Wb[3][i * CH + o];
    }
    const int j = base + lj;  // grid covers exactly NPTS (2500*8)
    g_G[j * CH + o] = csh[lj][0] * a0 + csh[lj][1] * a1 + csh[lj][2] * a2 + a3;
}

// ---------------------------------------------------------------------------
// Phase 2: out[n][o] = sum_{k: mask[n][k]} G[idx[n][k]][o]
// 8 points per block; idx/mask staged in LDS; G gathers are 128B coalesced
// per (n,k) and L2-resident (G = 2.56 MB).
// ---------------------------------------------------------------------------
__global__ __launch_bounds__(256) void gather_sum(
    const int* __restrict__ nbr_idx, const unsigned char* __restrict__ mask_b,
    float* __restrict__ out) {
    __shared__ int sidx[PTS_PER_BLOCK][KNB];
    __shared__ int smsk[PTS_PER_BLOCK][KNB];

    const int t = threadIdx.x;
    const int base = blockIdx.x * PTS_PER_BLOCK;

    if (t < PTS_PER_BLOCK * KNB) {  // 104 loads
        const int p = base * KNB + t;
        sidx[t / KNB][t % KNB] = nbr_idx[p];
        const int mode = g_mask_is_bytes;  // L2-broadcast scalar
        smsk[t / KNB][t % KNB] =
            mode ? (int)mask_b[p] : ((const int*)mask_b)[p];
    }
    __syncthreads();

    const int lj = t >> 5;
    const int o  = t & 31;
    float acc = 0.f;
    #pragma unroll
    for (int k = 0; k < KNB; ++k) {
        if (smsk[lj][k]) acc += g_G[sidx[lj][k] * CH + o];
    }
    out[base * CH + t] = acc;  // == out[(base+lj)*CH + o], coalesced
}

extern "C" void kernel_launch(void* const* d_in, const int* in_sizes, int n_in,
                              void* d_out, int out_size, void* d_ws, size_t ws_size,
                              hipStream_t stream) {
    const float* feats  = (const float*)d_in[0];
    const float* coords = (const float*)d_in[1];
    const float* W      = (const float*)d_in[2];
    const float* b      = (const float*)d_in[3];
    const int*   nidx   = (const int*)d_in[4];
    const unsigned char* nmask = (const unsigned char*)d_in[5];
    float* out = (float*)d_out;

    const int nblocks = NPTS / PTS_PER_BLOCK;  // 2500 exactly

    detect_mask_mode<<<1, 64, 0, stream>>>(nmask);
    precompute_G<<<nblocks, 256, 0, stream>>>(feats, coords, W, b);
    gather_sum<<<nblocks, 256, 0, stream>>>(nidx, nmask, out);
}

// Round 2
// 20.958 us; speedup vs baseline: 1.4141x; 1.4141x over previous
//
#include <hip/hip_runtime.h>
#include <hip/hip_bf16.h>

#define NPTS 20000
#define KNB 13
#define CH 32
#define MT 16                 // points per M-tile = one wave's MFMA D-tile rows
#define NTILES (NPTS / MT)    // 1250 exactly
#define PTS_PER_BLOCK 8       // gather kernel: 8 points * 32 ch = 256 threads

typedef __attribute__((ext_vector_type(8))) short bf16x8;
typedef __attribute__((ext_vector_type(4))) float f32x4;

// Per-point precomputed contribution G[j][o] (f32).
__device__ float g_G[NPTS * CH];

// f32 -> bf16 with round-to-nearest-even.
static __device__ __forceinline__ short f2bf(float x) {
    union { float f; unsigned u; } v; v.f = x;
    unsigned r = (v.u + 0x7FFFu + ((v.u >> 16) & 1u)) >> 16;
    return (short)r;
}

// ---------------------------------------------------------------------------
// Phase 1 (MFMA): G = Aug @ Wa
//   Aug[j] = [feats[j]*c0, feats[j]*c1, feats[j]*c2, feats[j]]  (len 128)
//   Wa     = [W0; W1; W2; B]                                    (128 x 32)
// One wave per 16-point tile. v_mfma_f32_16x16x32_bf16:
//   A: m = lane&15, k = 8*(lane>>4)+e   (K-tile kt => kappa = kt*32 + k)
//   B: n = lane&15, k = 8*(lane>>4)+e   (N split into 2 tiles of 16)
//   D: n = lane&15, m = 4*(lane>>4)+reg (m89-verified)
// K-tile kt coincides exactly with d-block kt of Aug => A-frag = feats-chunk
// scaled by coords[.][kt] (kt<3) or unscaled (kt=3).
// ---------------------------------------------------------------------------
__global__ __launch_bounds__(64) void precompute_G(
    const float* __restrict__ feats, const float* __restrict__ coords,
    const float* __restrict__ W, const float* __restrict__ bias) {
    const int tile = blockIdx.x;       // 0..1249
    const int base = tile * MT;
    const int l    = threadIdx.x;      // 0..63
    const int r15  = l & 15;           // A-row (point) / B-col (channel) / D-col
    const int g    = l >> 4;           // 0..3
    const int k8   = g * 8;

    // feats[base+r15][k8 .. k8+7]  (16B-aligned: ((base+r15)*32 + k8)*4 % 16 == 0)
    const float4* fp = (const float4*)(feats + (base + r15) * CH + k8);
    const float4 fa = fp[0], fb = fp[1];
    const float f[8] = {fa.x, fa.y, fa.z, fa.w, fb.x, fb.y, fb.z, fb.w};
    const float c0 = coords[(base + r15) * 3 + 0];
    const float c1 = coords[(base + r15) * 3 + 1];
    const float c2 = coords[(base + r15) * 3 + 2];

    // A-fragments: 4 K-tiles.
    bf16x8 aF0, aF1, aF2, aF3;
    #pragma unroll
    for (int e = 0; e < 8; ++e) {
        aF0[e] = f2bf(f[e] * c0);
        aF1[e] = f2bf(f[e] * c1);
        aF2[e] = f2bf(f[e] * c2);
        aF3[e] = f2bf(f[e]);
    }

    // B-fragments: Wa[kt*32 + k][nt*16 + r15], k = k8+e. All waves read the
    // same 16 KB => L2 broadcast.
    bf16x8 bF[4][2];
    #pragma unroll
    for (int kt = 0; kt < 4; ++kt) {
        const float* src = (kt < 3) ? (W + kt * 1024) : bias;
        #pragma unroll
        for (int nt = 0; nt < 2; ++nt) {
            #pragma unroll
            for (int e = 0; e < 8; ++e)
                bF[kt][nt][e] = f2bf(src[(k8 + e) * CH + nt * 16 + r15]);
        }
    }

    f32x4 acc0 = {0.f, 0.f, 0.f, 0.f};
    f32x4 acc1 = {0.f, 0.f, 0.f, 0.f};
    acc0 = __builtin_amdgcn_mfma_f32_16x16x32_bf16(aF0, bF[0][0], acc0, 0, 0, 0);
    acc1 = __builtin_amdgcn_mfma_f32_16x16x32_bf16(aF0, bF[0][1], acc1, 0, 0, 0);
    acc0 = __builtin_amdgcn_mfma_f32_16x16x32_bf16(aF1, bF[1][0], acc0, 0, 0, 0);
    acc1 = __builtin_amdgcn_mfma_f32_16x16x32_bf16(aF1, bF[1][1], acc1, 0, 0, 0);
    acc0 = __builtin_amdgcn_mfma_f32_16x16x32_bf16(aF2, bF[2][0], acc0, 0, 0, 0);
    acc1 = __builtin_amdgcn_mfma_f32_16x16x32_bf16(aF2, bF[2][1], acc1, 0, 0, 0);
    acc0 = __builtin_amdgcn_mfma_f32_16x16x32_bf16(aF3, bF[3][0], acc0, 0, 0, 0);
    acc1 = __builtin_amdgcn_mfma_f32_16x16x32_bf16(aF3, bF[3][1], acc1, 0, 0, 0);

    // D[m][n]: point m = 4*g + reg, channel n = r15 (+16 for acc1).
    #pragma unroll
    for (int r = 0; r < 4; ++r) {
        const int m = g * 4 + r;
        g_G[(base + m) * CH + r15]      = acc0[r];
        g_G[(base + m) * CH + 16 + r15] = acc1[r];
    }
}

// ---------------------------------------------------------------------------
// Phase 2: out[n][o] = sum_{k: mask[n][k]} G[idx[n][k]][o]
// Mask buffer may be 1-byte bool or 4-byte int32; each block self-detects:
// in int32 layout of 0/1 values every byte at offset %4 != 0 is zero; in
// byte layout ~half of the 768 sampled positions are nonzero (miss prob
// 2^-768). Deterministic, no cross-kernel state.
// ---------------------------------------------------------------------------
__global__ __launch_bounds__(256) void gather_sum(
    const int* __restrict__ nbr_idx, const unsigned char* __restrict__ mask_b,
    float* __restrict__ out) {
    __shared__ int sidx[PTS_PER_BLOCK][KNB];

    const int t = threadIdx.x;
    const int base = blockIdx.x * PTS_PER_BLOCK;

    // Self-detect mask mode from first 1024 bytes (both layouts >= 260000 B).
    const int p0 = t * 4;
    const int pred = (mask_b[p0 + 1] | mask_b[p0 + 2] | mask_b[p0 + 3]) != 0;
    const int is_bytes = __syncthreads_or(pred);

    if (t < PTS_PER_BLOCK * KNB) {  // 104 loads
        const int p = base * KNB + t;
        const int m = is_bytes ? (int)mask_b[p] : ((const int*)mask_b)[p];
        sidx[t / KNB][t % KNB] = m ? nbr_idx[p] : -1;
    }
    __syncthreads();

    const int lj = t >> 5;
    const int o  = t & 31;
    float acc = 0.f;
    #pragma unroll
    for (int k = 0; k < KNB; ++k) {
        const int j = sidx[lj][k];
        if (j >= 0) acc += g_G[j * CH + o];  // 128B coalesced, L2-resident
    }
    out[base * CH + t] = acc;  // coalesced
}

extern "C" void kernel_launch(void* const* d_in, const int* in_sizes, int n_in,
                              void* d_out, int out_size, void* d_ws, size_t ws_size,
                              hipStream_t stream) {
    const float* feats  = (const float*)d_in[0];
    const float* coords = (const float*)d_in[1];
    const float* W      = (const float*)d_in[2];
    const float* bias   = (const float*)d_in[3];
    const int*   nidx   = (const int*)d_in[4];
    const unsigned char* nmask = (const unsigned char*)d_in[5];
    float* out = (float*)d_out;

    precompute_G<<<NTILES, 64, 0, stream>>>(feats, coords, W, bias);
    gather_sum<<<NPTS / PTS_PER_BLOCK, 256, 0, stream>>>(nidx, nmask, out);
}

// Round 3
// 14.210 us; speedup vs baseline: 2.0855x; 1.4749x over previous
//
#include <hip/hip_runtime.h>
#include <hip/hip_bf16.h>

#define NPTS 20000
#define KNB 13
#define CH 32
#define PPW 4                                  // points per wave
#define WVB 4                                  // waves per block
#define PTS_PER_BLOCK (PPW * WVB)              // 16
#define NBLOCKS (NPTS / PTS_PER_BLOCK)         // 1250 exactly

typedef __attribute__((ext_vector_type(8))) short bf16x8;
typedef __attribute__((ext_vector_type(4))) float f32x4;

// f32 -> bf16, round-half-up (2 ops; |err| <= 2^-9 rel, margin is 6x).
static __device__ __forceinline__ short f2bf(float x) {
    union { float f; unsigned u; } v; v.f = x;
    return (short)((v.u + 0x8000u) >> 16);
}

// ---------------------------------------------------------------------------
// Fully fused: one wave per point-group. For each point n, its <=13 masked
// neighbors are rows m of a 16x128 Aug tile:
//   Aug[m] = [feats[j]*c0, feats[j]*c1, feats[j]*c2, feats[j]],  j=idx[n][m]
// D = Aug @ Wa  (Wa = [W0;W1;W2;B], 128x32) via 8x mfma_f32_16x16x32_bf16
// (lane mapping verified end-to-end in round 2), then out[n][:] = sum_m D[m][:]
// (rows m>=13 / masked rows are zeroed in A => contribute 0).
// Row-sum: each lane holds D[4g+r][r15(+16)] -> 4 reg adds + shfl_xor 16/32.
// No LDS, no __syncthreads, one dispatch.
// ---------------------------------------------------------------------------
__global__ __launch_bounds__(256) void fused_conv(
    const float* __restrict__ feats, const float* __restrict__ coords,
    const float* __restrict__ W, const float* __restrict__ bias,
    const int* __restrict__ nbr_idx, const unsigned char* __restrict__ mask_b,
    float* __restrict__ out) {

    const int l   = threadIdx.x & 63;
    const int w   = threadIdx.x >> 6;
    const int r15 = l & 15;   // A-row (pair) / B-col (channel) / D-col
    const int g   = l >> 4;   // 0..3
    const int k8  = g * 8;

    // --- mask dtype self-detect, per wave, no barrier ---------------------
    // int32 layout of 0/1 => every byte at offset %4 != 0 is zero; byte
    // layout => ~half of 192 sampled bytes nonzero (miss prob 2^-192).
    const int p0 = l * 4;
    const int pred = (mask_b[p0 + 1] | mask_b[p0 + 2] | mask_b[p0 + 3]) != 0;
    const bool bytes_mode = (__ballot(pred) != 0ull);

    // --- B fragments: Wa[(k8+e)*32 + nt*16 + r15], L2-broadcast, loaded
    // once per wave and reused for all PPW points. ------------------------
    bf16x8 bF[4][2];
    #pragma unroll
    for (int kt = 0; kt < 4; ++kt) {
        const float* src = (kt < 3) ? (W + kt * (CH * CH)) : bias;
        #pragma unroll
        for (int nt = 0; nt < 2; ++nt) {
            #pragma unroll
            for (int e = 0; e < 8; ++e)
                bF[kt][nt][e] = f2bf(src[(k8 + e) * CH + nt * 16 + r15]);
        }
    }

    const int n0 = (blockIdx.x * WVB + w) * PPW;

    #pragma unroll
    for (int pp = 0; pp < PPW; ++pp) {
        const int n = n0 + pp;

        int valid = 0, j = 0;
        if (r15 < KNB) {
            const int p = n * KNB + r15;
            j = nbr_idx[p];
            const int mv = bytes_mode ? (int)mask_b[p] : ((const int*)mask_b)[p];
            valid = (mv != 0);
        }
        const int ja = valid ? j : 0;   // safe row; zeroed via vs below

        // feats[ja][k8..k8+7] : 16B-aligned, each 16-lane group covers 8
        // consecutive floats -> wave collectively reads each row once.
        const float4* fp = (const float4*)(feats + ja * CH + k8);
        const float4 fa = fp[0], fb = fp[1];
        const float f[8] = {fa.x, fa.y, fa.z, fa.w, fb.x, fb.y, fb.z, fb.w};
        const float vs = valid ? 1.0f : 0.0f;
        const float c0 = coords[ja * 3 + 0] * vs;
        const float c1 = coords[ja * 3 + 1] * vs;
        const float c2 = coords[ja * 3 + 2] * vs;

        bf16x8 a0, a1, a2, a3;
        #pragma unroll
        for (int e = 0; e < 8; ++e) {
            const float fe = f[e];
            a0[e] = f2bf(fe * c0);
            a1[e] = f2bf(fe * c1);
            a2[e] = f2bf(fe * c2);
            a3[e] = f2bf(fe * vs);
        }

        f32x4 acc0 = {0.f, 0.f, 0.f, 0.f};
        f32x4 acc1 = {0.f, 0.f, 0.f, 0.f};
        acc0 = __builtin_amdgcn_mfma_f32_16x16x32_bf16(a0, bF[0][0], acc0, 0, 0, 0);
        acc1 = __builtin_amdgcn_mfma_f32_16x16x32_bf16(a0, bF[0][1], acc1, 0, 0, 0);
        acc0 = __builtin_amdgcn_mfma_f32_16x16x32_bf16(a1, bF[1][0], acc0, 0, 0, 0);
        acc1 = __builtin_amdgcn_mfma_f32_16x16x32_bf16(a1, bF[1][1], acc1, 0, 0, 0);
        acc0 = __builtin_amdgcn_mfma_f32_16x16x32_bf16(a2, bF[2][0], acc0, 0, 0, 0);
        acc1 = __builtin_amdgcn_mfma_f32_16x16x32_bf16(a2, bF[2][1], acc1, 0, 0, 0);
        acc0 = __builtin_amdgcn_mfma_f32_16x16x32_bf16(a3, bF[3][0], acc0, 0, 0, 0);
        acc1 = __builtin_amdgcn_mfma_f32_16x16x32_bf16(a3, bF[3][1], acc1, 0, 0, 0);

        // Row-sum over all 16 rows (invalid rows are zero).
        float s0 = acc0[0] + acc0[1] + acc0[2] + acc0[3];
        float s1 = acc1[0] + acc1[1] + acc1[2] + acc1[3];
        s0 += __shfl_xor(s0, 16); s0 += __shfl_xor(s0, 32);
        s1 += __shfl_xor(s1, 16); s1 += __shfl_xor(s1, 32);

        // Lane l<16 has channel l (s0); lane 16..31 has channel l (s1).
        if (l < 32) out[n * CH + l] = (l < 16) ? s0 : s1;  // 128B contiguous
    }
}

extern "C" void kernel_launch(void* const* d_in, const int* in_sizes, int n_in,
                              void* d_out, int out_size, void* d_ws, size_t ws_size,
                              hipStream_t stream) {
    const float* feats  = (const float*)d_in[0];
    const float* coords = (const float*)d_in[1];
    const float* W      = (const float*)d_in[2];
    const float* bias   = (const float*)d_in[3];
    const int*   nidx   = (const int*)d_in[4];
    const unsigned char* nmask = (const unsigned char*)d_in[5];
    float* out = (float*)d_out;

    fused_conv<<<NBLOCKS, 256, 0, stream>>>(feats, coords, W, bias, nidx, nmask, out);
}